// Round 6
// baseline (2899.324 us; speedup 1.0000x reference)
//
#include <hip/hip_runtime.h>
#include <hip/hip_bf16.h>
#include <math.h>

#define BS   4096
#define ZD   512
#define HIDN 1024
#define ZINN 128
#define NST  32
#define NP   3072   // 3*HIDN, gate-interleaved column space (96 = 3x32 groups)

typedef unsigned short u16;
typedef __bf16 bf16x8 __attribute__((ext_vector_type(8)));
typedef float f32x4 __attribute__((ext_vector_type(4)));
typedef float f32x16 __attribute__((ext_vector_type(16)));

static __device__ __forceinline__ u16 bf_bits(float v) {
  __bf16 b = (__bf16)v;
  return __builtin_bit_cast(unsigned short, b);
}
static __device__ __forceinline__ float bf_val(float v) {
  return (float)(__bf16)v;
}

// async global -> LDS, 16 bytes per lane. LDS dest = wave-uniform base + lane*16.
static __device__ __forceinline__ void ld_lds16(const u16* g, u16* l) {
  __builtin_amdgcn_global_load_lds(
      (const __attribute__((address_space(1))) void*)g,
      (__attribute__((address_space(3))) void*)l, 16, 0, 0);
}

// W' row w -> original W_hh/W_ih row. 32-granular interleave for 32x32 MFMA:
// w = g*96 + j*32 + m  ->  j*1024 + g*32 + m   (j = gate r/u/n, m = h-col within group)
static __device__ __forceinline__ int r_orig(int w) {
  const int g = w / 96;
  const int rem = w - g * 96;
  const int j = rem >> 5, m = rem & 31;
  return j * 1024 + g * 32 + m;
}

// ---------------- fragment-major packed layout ----------------
// Pk organized as [row-group (rows/32)][q = k/16][pass hi/lo][64 lanes x 8 u16].
// Within a block, lane slot l = ((k>>3)&1)*32 + (row&31) holds its 8 k-elems —
// i.e. EXACTLY the mfma_32x32x16 A/B fragment order. ds_read_b128 at base+lane*16
// is therefore perfectly lane-linear (zero bank conflicts), and global_load_lds
// staging is linear 1KB pass-blocks (global block order == LDS block order).
static __device__ __forceinline__ size_t pk_off(int row, int col) {
  return ((size_t)(row >> 5) * 64 + (col >> 4)) * 1024 +
         (((col >> 3) & 1) * 32 + (row & 31)) * 8 + (col & 7);
}
static __device__ __forceinline__ void pack_write(u16* __restrict__ P, int row, int col, float v) {
  const size_t off = pk_off(row, col);
  const float h = bf_val(v);
  P[off] = bf_bits(v);            // hi pass
  P[off + 512] = bf_bits(v - h);  // lo pass (+1KB)
}

// ---------------- prep kernels ----------------

__global__ void k_split(const float* __restrict__ s, u16* __restrict__ hi,
                        u16* __restrict__ lo, int n) {
  int i = blockIdx.x * 256 + threadIdx.x;
  if (i >= n) return;
  float v = s[i];
  float h = bf_val(v);
  hi[i] = bf_bits(v);
  lo[i] = bf_bits(v - h);
}

// W_hh -> fragment-major Bpk with gate-interleaved row reorder
__global__ void k_pack_whh(const float* __restrict__ W_hh, u16* __restrict__ Bpk) {
  int i = blockIdx.x * 256 + threadIdx.x;
  if (i >= NP * HIDN) return;
  const int w = i >> 10, k = i & 1023;
  const float v = W_hh[(size_t)r_orig(w) * HIDN + k];
  pack_write(Bpk, w, k, v);
}

// W_ih[:,3:131] -> split (reordered rows); W_ih[:,0:3] -> wtok (reordered); cb0 (reordered)
__global__ void k_prep_wih(const float* __restrict__ W_ih, const float* __restrict__ b_ih,
                           const float* __restrict__ b_hh,
                           u16* __restrict__ whi, u16* __restrict__ wlo,
                           float* __restrict__ wtok, float* __restrict__ cb0) {
  int i = blockIdx.x * 256 + threadIdx.x;
  if (i < NP * 128) {
    const int w = i >> 7, c = i & 127;
    const int r = r_orig(w);
    const float v = W_ih[r * 131 + 3 + c];
    const float h = bf_val(v);
    whi[i] = bf_bits(v);
    wlo[i] = bf_bits(v - h);
  }
  if (i < NP * 3) {
    const int w = i / 3, s = i - w * 3;
    wtok[i] = W_ih[r_orig(w) * 131 + s];
  }
  if (i < NP) {
    const int r = r_orig(i);
    cb0[i] = b_ih[r] + (r < 2048 ? b_hh[r] : 0.0f);
  }
}

__global__ void k_token_init(const float* __restrict__ init_input, float* __restrict__ token) {
  int i = blockIdx.x * 256 + threadIdx.x;
  if (i < BS * 4) token[i] = ((i & 3) < 3) ? init_input[i & 3] : 0.0f;
}

// ---------------- generic split-3 GEMM (prep only): C = A*B^T (+bias) ----------------
// OUTMODE: 0 = f32 only, 1 = f32 + plain hi/lo splits, 2 = f32 + fragment-major Apk
template <int OUTMODE>
__global__ __launch_bounds__(256) void k_gemm(
    const u16* __restrict__ Ahi, const u16* __restrict__ Alo,
    const u16* __restrict__ Bhi, const u16* __restrict__ Blo,
    const float* __restrict__ bias,
    float* __restrict__ C, u16* __restrict__ Chi, u16* __restrict__ Clo,
    u16* __restrict__ Apk, int N, int K) {
  __shared__ __align__(16) u16 sAhi[128 * 64];
  __shared__ __align__(16) u16 sAlo[128 * 64];
  __shared__ __align__(16) u16 sBhi[128 * 64];
  __shared__ __align__(16) u16 sBlo[128 * 64];

  const int t = threadIdx.x;
  const int row0 = blockIdx.y * 128, col0 = blockIdx.x * 128;
  const int wave = t >> 6, lane = t & 63;
  const int w64 = wave * 64;
  const int wm = (wave & 1) * 64, wn = (wave >> 1) * 64;
  const int lm = lane & 15, lq = lane >> 4;
  const int pb = lm & 7;

  f32x4 acc[4][4] = {};

  int sm[4], skc[4], sub[4];
#pragma unroll
  for (int i = 0; i < 4; ++i) {
    const int u = i * 256 + t;
    sm[i] = u >> 3;
    skc[i] = (u & 7) ^ (sm[i] & 7);
    sub[i] = (i * 256 + w64) * 8;
  }

  const int nk = K >> 6;
  for (int kt = 0; kt < nk; ++kt) {
    const int k0 = kt << 6;
    __syncthreads();
#pragma unroll
    for (int i = 0; i < 4; ++i) {
      const size_t ga = (size_t)(row0 + sm[i]) * K + k0 + skc[i] * 8;
      const size_t gb = (size_t)(col0 + sm[i]) * K + k0 + skc[i] * 8;
      ld_lds16(Ahi + ga, &sAhi[sub[i]]);
      ld_lds16(Alo + ga, &sAlo[sub[i]]);
      ld_lds16(Bhi + gb, &sBhi[sub[i]]);
      ld_lds16(Blo + gb, &sBlo[sub[i]]);
    }
    __syncthreads();
#pragma unroll
    for (int kk = 0; kk < 2; ++kk) {
      const int pos = ((kk * 4 + lq) ^ pb) * 8;
      bf16x8 ah[4], al[4], bh[4], bl[4];
#pragma unroll
      for (int i = 0; i < 4; ++i) {
        const int ma = (wm + i * 16 + lm) * 64;
        const int mb = (wn + i * 16 + lm) * 64;
        ah[i] = *(const bf16x8*)&sAhi[ma + pos];
        al[i] = *(const bf16x8*)&sAlo[ma + pos];
        bh[i] = *(const bf16x8*)&sBhi[mb + pos];
        bl[i] = *(const bf16x8*)&sBlo[mb + pos];
      }
#pragma unroll
      for (int i = 0; i < 4; ++i)
#pragma unroll
        for (int j = 0; j < 4; ++j) {
          acc[i][j] = __builtin_amdgcn_mfma_f32_16x16x32_bf16(ah[i], bh[j], acc[i][j], 0, 0, 0);
          acc[i][j] = __builtin_amdgcn_mfma_f32_16x16x32_bf16(al[i], bh[j], acc[i][j], 0, 0, 0);
          acc[i][j] = __builtin_amdgcn_mfma_f32_16x16x32_bf16(ah[i], bl[j], acc[i][j], 0, 0, 0);
        }
    }
  }

#pragma unroll
  for (int i = 0; i < 4; ++i) {
    const int grow = row0 + wm + i * 16 + lq * 4;
#pragma unroll
    for (int j = 0; j < 4; ++j) {
      const int gcol = col0 + wn + j * 16 + lm;
      const float bs = bias ? bias[gcol] : 0.0f;
#pragma unroll
      for (int d = 0; d < 4; ++d) {
        const float v = acc[i][j][d] + bs;
        const size_t idx = (size_t)(grow + d) * N + gcol;
        C[idx] = v;
        if (OUTMODE == 1) {
          const float h = bf_val(v);
          Chi[idx] = bf_bits(v);
          Clo[idx] = bf_bits(v - h);
        }
        if (OUTMODE == 2) {
          pack_write(Apk, grow + d, gcol, v);
        }
      }
    }
  }
}

// ---------------- fused gh-GEMM + GRU gate kernel (v6: lane-linear LDS) ----------------
// Same pipeline as v5 (128M x 192N', BK=32, dbuf 80KB, 2 blk/CU, 8 waves 4Mx2N,
// one __syncthreads per K-tile, STAGE(next) right after barrier). ONE change:
// operands live in fragment-major blocks so every ds_read_b128 is base+lane*16
// (zero bank conflicts) — v5 measured exactly 4.0 conflicts/read, and the CU-shared
// LDS unit was ~85% busy: the real plateau resource across v2..v5.

#define SZA5 (128 * 64)
#define SZB5 (192 * 64)
#define MF(a, b, c) c = __builtin_amdgcn_mfma_f32_32x32x16_bf16(a, b, c, 0, 0, 0)

__global__ __launch_bounds__(512, 4) void k_fused6(
    const u16* __restrict__ Apk,   // fragment-major h splits [128 rg][64 q][2 pass][512 u16]
    const u16* __restrict__ Bpk,   // fragment-major Whh'     [96 rg][64 q][2 pass][512 u16]
    const float* __restrict__ C0,  // [4096][3072] W'-order
    const float* __restrict__ token,
    const float* __restrict__ wtok,
    const float* __restrict__ b_hh,
    const float* __restrict__ h_in, float* __restrict__ h_out,
    u16* __restrict__ Apk_out) {
  __shared__ __align__(16) u16 sA[2 * SZA5];   // [4 g][2 qq][2 pass][512 u16] per buf
  __shared__ __align__(16) u16 sB[2 * SZB5];   // [6 g][2 qq][2 pass][512 u16] per buf

  const int t = threadIdx.x;
  const int wave = t >> 6, lane = t & 63;
  const int row0 = blockIdx.y * 128;
  const int colW0 = blockIdx.x * 192;
  const int wm = (wave >> 1) * 32;   // 4 M-waves x 32 rows
  const int wn = (wave & 1) * 96;    // 2 N-waves x 96 W-rows (one gate-triple group)
  const int lr = lane & 31, lh = lane >> 5;

  f32x16 acc0 = {}, acc1 = {}, acc2 = {};

  // ---- staging decomposition: 16 A pass-blocks + 24 B pass-blocks per tile, 5/wave ----
  // A: wave w loads (g = w>>1, qq = w&1), pass 0 and 1.
  const u16* asrc = Apk + ((size_t)((row0 >> 5) + (wave >> 1)) * 64 + (wave & 1)) * 1024 + lane * 8;
  const int aw = (wave >> 1) * 2048 + (wave & 1) * 1024;  // LDS base (u16), +pass*512
  // B: id = wave*3 + j -> (g = id>>2, qq = (id>>1)&1, pass = id&1)
  const int id0 = wave * 3;
  const int bg0 = (id0 + 0) >> 2, bq0 = ((id0 + 0) >> 1) & 1, bp0 = (id0 + 0) & 1;
  const int bg1 = (id0 + 1) >> 2, bq1 = ((id0 + 1) >> 1) & 1, bp1 = (id0 + 1) & 1;
  const int bg2 = (id0 + 2) >> 2, bq2 = ((id0 + 2) >> 1) & 1, bp2 = (id0 + 2) & 1;
  const u16* bsrc0 = Bpk + ((size_t)((colW0 >> 5) + bg0) * 64 + bq0) * 1024 + bp0 * 512 + lane * 8;
  const u16* bsrc1 = Bpk + ((size_t)((colW0 >> 5) + bg1) * 64 + bq1) * 1024 + bp1 * 512 + lane * 8;
  const u16* bsrc2 = Bpk + ((size_t)((colW0 >> 5) + bg2) * 64 + bq2) * 1024 + bp2 * 512 + lane * 8;
  const int bw0 = bg0 * 2048 + bq0 * 1024 + bp0 * 512;
  const int bw1 = bg1 * 2048 + bq1 * 1024 + bp1 * 512;
  const int bw2 = bg2 * 2048 + bq2 * 1024 + bp2 * 512;

#define STAGE(kt_, ab, bb)                                            \
  ld_lds16(asrc + (size_t)(kt_) * 2048,       &sA[(ab) + aw]);        \
  ld_lds16(asrc + (size_t)(kt_) * 2048 + 512, &sA[(ab) + aw + 512]);  \
  ld_lds16(bsrc0 + (size_t)(kt_) * 2048, &sB[(bb) + bw0]);            \
  ld_lds16(bsrc1 + (size_t)(kt_) * 2048, &sB[(bb) + bw1]);            \
  ld_lds16(bsrc2 + (size_t)(kt_) * 2048, &sB[(bb) + bw2]);

  // ---- fragment read bases (lane-linear) ----
  const int agA = (wave >> 1) * 2048;            // + kk*1024 (+0 hi, +512 lo)
  const int bgB = (wave & 1) * 3 * 2048;         // group base; + j*2048 + kk*1024
  const int l8 = lane * 8;

  STAGE(0, 0, 0);
  __syncthreads();

#pragma unroll 1
  for (int kt = 0; kt < 32; ++kt) {
    const int ab = (kt & 1) ? SZA5 : 0, bb = (kt & 1) ? SZB5 : 0;
    const int an = (kt & 1) ? 0 : SZA5, bn = (kt & 1) ? 0 : SZB5;
    if (kt < 31) { STAGE(kt + 1, an, bn); }
#pragma unroll
    for (int kk = 0; kk < 2; ++kk) {
      const int ka = ab + agA + kk * 1024 + l8;
      const bf16x8 ah = *(const bf16x8*)&sA[ka];
      const bf16x8 al = *(const bf16x8*)&sA[ka + 512];
      const int kb = bb + bgB + kk * 1024 + l8;
      const bf16x8 b0h = *(const bf16x8*)&sB[kb];
      const bf16x8 b0l = *(const bf16x8*)&sB[kb + 512];
      const bf16x8 b1h = *(const bf16x8*)&sB[kb + 2048];
      const bf16x8 b1l = *(const bf16x8*)&sB[kb + 2048 + 512];
      const bf16x8 b2h = *(const bf16x8*)&sB[kb + 4096];
      const bf16x8 b2l = *(const bf16x8*)&sB[kb + 4096 + 512];
      MF(ah, b0h, acc0); MF(ah, b1h, acc1); MF(ah, b2h, acc2);
      MF(al, b0h, acc0); MF(al, b1h, acc1); MF(al, b2h, acc2);
      MF(ah, b0l, acc0); MF(ah, b1l, acc1); MF(ah, b2l, acc2);
    }
    __syncthreads();
  }
#undef STAGE

  // ---- fused GRU epilogue (exact f32) ----
  // Lane owns h-col c; acc0/1/2 are r/u/n gates for that col (96 = 3x32 interleave).
  const int w0 = colW0 + wn + lr;                  // W'-row of r-gate
  const int c = ((colW0 + wn) / 96) * 32 + lr;     // h-col
  float wt[3][3];
#pragma unroll
  for (int j = 0; j < 3; ++j) {
    wt[j][0] = wtok[(w0 + j * 32) * 3 + 0];
    wt[j][1] = wtok[(w0 + j * 32) * 3 + 1];
    wt[j][2] = wtok[(w0 + j * 32) * 3 + 2];
  }
  const float bn = b_hh[2048 + c];
  const int cq = c >> 4, ckh = (c >> 3) & 1, ce = c & 7;
#pragma unroll
  for (int d = 0; d < 16; ++d) {
    const int row = row0 + wm + 4 * lh + (d & 3) + 8 * (d >> 2);
    const float4 tk = *(const float4*)&token[row * 4];
    const size_t cb = (size_t)row * NP;
    const float pr = C0[cb + w0]      + acc0[d] + tk.x * wt[0][0] + tk.y * wt[0][1] + tk.z * wt[0][2];
    const float pu = C0[cb + w0 + 32] + acc1[d] + tk.x * wt[1][0] + tk.y * wt[1][1] + tk.z * wt[1][2];
    const float pn = C0[cb + w0 + 64] + tk.x * wt[2][0] + tk.y * wt[2][1] + tk.z * wt[2][2];
    const float hn = acc2[d] + bn;
    const float r = 1.0f / (1.0f + expf(-pr));
    const float u = 1.0f / (1.0f + expf(-pu));
    const float n = tanhf(pn + r * hn);
    const size_t hidx = (size_t)row * HIDN + c;
    const float hv = (1.0f - u) * n + u * h_in[hidx];
    h_out[hidx] = hv;
    const size_t poff = ((size_t)(row >> 5) * 64 + cq) * 1024 + (ckh * 32 + (row & 31)) * 8 + ce;
    const float hh = bf_val(hv);
    Apk_out[poff] = bf_bits(hv);
    Apk_out[poff + 512] = bf_bits(hv - hh);
  }
}
#undef MF

// ---------------- per-step output kernel ----------------
__global__ __launch_bounds__(256) void k_out(
    const float* __restrict__ h, const float* __restrict__ W_out,
    const float* __restrict__ b_out,
    float* __restrict__ out, float* __restrict__ token, int step) {
  const int wave = threadIdx.x >> 6, lane = threadIdx.x & 63;
  const int row = blockIdx.x * 4 + wave;
  const float4* hp = (const float4*)(h + (size_t)row * 1024);
  const float4* w0p = (const float4*)(W_out);
  const float4* w1p = (const float4*)(W_out + 1024);
  const float4* w2p = (const float4*)(W_out + 2048);
  float s0 = 0.f, s1 = 0.f, s2 = 0.f;
#pragma unroll
  for (int c = 0; c < 4; ++c) {
    const int k = lane + 64 * c;
    const float4 hv = hp[k];
    const float4 a = w0p[k], bq = w1p[k], cq = w2p[k];
    s0 += hv.x * a.x + hv.y * a.y + hv.z * a.z + hv.w * a.w;
    s1 += hv.x * bq.x + hv.y * bq.y + hv.z * bq.z + hv.w * bq.w;
    s2 += hv.x * cq.x + hv.y * cq.y + hv.z * cq.z + hv.w * cq.w;
  }
#pragma unroll
  for (int off = 32; off > 0; off >>= 1) {
    s0 += __shfl_xor(s0, off, 64);
    s1 += __shfl_xor(s1, off, 64);
    s2 += __shfl_xor(s2, off, 64);
  }
  if (lane == 0) {
    const float o0 = s0 + b_out[0];
    const float o1 = s1 + b_out[1];
    const float o2 = s2 + b_out[2];
    const float bass = 1.0f / (1.0f + expf(-o0));
    const float rhy = 1.0f / (1.0f + expf(-o2));
    const size_t ob = ((size_t)row * NST + step) * 3;
    out[ob + 0] = bass;
    out[ob + 1] = o1;
    out[ob + 2] = rhy;
    token[row * 4 + 0] = bass;
    token[row * 4 + 1] = o1;
    token[row * 4 + 2] = (rhy > 0.5f) ? 1.0f : 0.0f;
  }
}

// ---------------- host ----------------
extern "C" void kernel_launch(void* const* d_in, const int* in_sizes, int n_in,
                              void* d_out, int out_size, void* d_ws, size_t ws_size,
                              hipStream_t stream) {
  const float* z = (const float*)d_in[0];
  const float* W_zh = (const float*)d_in[3];
  const float* b_zh = (const float*)d_in[4];
  const float* W_zi = (const float*)d_in[5];
  const float* b_zi = (const float*)d_in[6];
  const float* W_ih = (const float*)d_in[7];
  const float* b_ih = (const float*)d_in[8];
  const float* W_hh = (const float*)d_in[9];
  const float* b_hh = (const float*)d_in[10];
  const float* W_out = (const float*)d_in[11];
  const float* b_out = (const float*)d_in[12];
  const float* init_input = (const float*)d_in[13];
  float* out = (float*)d_out;

  char* p = (char*)d_ws;
  auto alloc = [&](size_t bytes) {
    char* q = p;
    p += (bytes + 255) & ~(size_t)255;
    return q;
  };
  float* h[2];
  u16* Apk[2];
  for (int s = 0; s < 2; ++s) {
    h[s] = (float*)alloc((size_t)BS * HIDN * 4);
    Apk[s] = (u16*)alloc((size_t)BS * 2048 * 2);
  }
  float* C0 = (float*)alloc((size_t)BS * NP * 4);
  u16* z_hi = (u16*)alloc((size_t)BS * ZD * 2);
  u16* z_lo = (u16*)alloc((size_t)BS * ZD * 2);
  float* zin = (float*)alloc((size_t)BS * ZINN * 4);
  u16* zin_hi = (u16*)alloc((size_t)BS * ZINN * 2);
  u16* zin_lo = (u16*)alloc((size_t)BS * ZINN * 2);
  u16* Wzh_hi = (u16*)alloc((size_t)HIDN * ZD * 2);
  u16* Wzh_lo = (u16*)alloc((size_t)HIDN * ZD * 2);
  u16* Wzi_hi = (u16*)alloc((size_t)ZINN * ZD * 2);
  u16* Wzi_lo = (u16*)alloc((size_t)ZINN * ZD * 2);
  u16* Wihz_hi = (u16*)alloc((size_t)NP * ZINN * 2);
  u16* Wihz_lo = (u16*)alloc((size_t)NP * ZINN * 2);
  u16* Bpk = (u16*)alloc((size_t)NP * 2048 * 2);
  float* wtok = (float*)alloc((size_t)NP * 3 * 4);
  float* cb0 = (float*)alloc((size_t)NP * 4);
  float* token = (float*)alloc((size_t)BS * 4 * 4);

  // ---- prep ----
  k_pack_whh<<<dim3((NP * HIDN + 255) / 256), 256, 0, stream>>>(W_hh, Bpk);
  k_split<<<dim3((HIDN * ZD + 255) / 256), 256, 0, stream>>>(W_zh, Wzh_hi, Wzh_lo, HIDN * ZD);
  k_split<<<dim3((ZINN * ZD + 255) / 256), 256, 0, stream>>>(W_zi, Wzi_hi, Wzi_lo, ZINN * ZD);
  k_split<<<dim3((BS * ZD + 255) / 256), 256, 0, stream>>>(z, z_hi, z_lo, BS * ZD);
  k_prep_wih<<<dim3((NP * 128 + 255) / 256), 256, 0, stream>>>(W_ih, b_ih, b_hh, Wihz_hi, Wihz_lo, wtok, cb0);
  k_token_init<<<dim3((BS * 4 + 255) / 256), 256, 0, stream>>>(init_input, token);

  // ---- prep GEMMs ----
  k_gemm<2><<<dim3(HIDN / 128, BS / 128), 256, 0, stream>>>(
      z_hi, z_lo, Wzh_hi, Wzh_lo, b_zh, h[0], nullptr, nullptr, Apk[0], HIDN, ZD);
  k_gemm<1><<<dim3(ZINN / 128, BS / 128), 256, 0, stream>>>(
      z_hi, z_lo, Wzi_hi, Wzi_lo, b_zi, zin, zin_hi, zin_lo, nullptr, ZINN, ZD);
  k_gemm<0><<<dim3(NP / 128, BS / 128), 256, 0, stream>>>(
      zin_hi, zin_lo, Wihz_hi, Wihz_lo, cb0, C0, nullptr, nullptr, nullptr, NP, ZINN);

  // ---- 32 recurrent steps ----
  for (int t = 0; t < NST; ++t) {
    const int cur = t & 1, nxt = (t + 1) & 1;
    k_fused6<<<dim3(NP / 192, BS / 128), 512, 0, stream>>>(
        Apk[cur], Bpk, C0, token, wtok, b_hh, h[cur], h[nxt], Apk[nxt]);
    k_out<<<dim3(BS / 4), 256, 0, stream>>>(h[nxt], W_out, b_out, out, token, t);
  }
  (void)in_sizes; (void)n_in; (void)out_size; (void)ws_size;
}

// Round 7
// 2335.520 us; speedup vs baseline: 1.2414x; 1.2414x over previous
//
#include <hip/hip_runtime.h>
#include <hip/hip_bf16.h>
#include <math.h>

#define BS   4096
#define ZD   512
#define HIDN 1024
#define ZINN 128
#define NST  32
#define NP   3072   // 3*HIDN, gate-interleaved column space (96 = 3x32 groups)

typedef unsigned short u16;
typedef __bf16 bf16x8 __attribute__((ext_vector_type(8)));
typedef _Float16 f16x8 __attribute__((ext_vector_type(8)));
typedef float f32x4 __attribute__((ext_vector_type(4)));
typedef float f32x16 __attribute__((ext_vector_type(16)));

static __device__ __forceinline__ u16 bf_bits(float v) {
  __bf16 b = (__bf16)v;
  return __builtin_bit_cast(unsigned short, b);
}
static __device__ __forceinline__ float bf_val(float v) {
  return (float)(__bf16)v;
}
static __device__ __forceinline__ u16 h16_bits(float v) {
  _Float16 h = (_Float16)v;
  return __builtin_bit_cast(unsigned short, h);
}
static __device__ __forceinline__ float h16_val(float v) {
  return (float)(_Float16)v;
}

// async global -> LDS, 16 bytes per lane. LDS dest = wave-uniform base + lane*16.
static __device__ __forceinline__ void ld_lds16(const u16* g, u16* l) {
  __builtin_amdgcn_global_load_lds(
      (const __attribute__((address_space(1))) void*)g,
      (__attribute__((address_space(3))) void*)l, 16, 0, 0);
}

// W' row w -> original W_hh/W_ih row. 32-granular interleave for 32x32 MFMA:
// w = g*96 + j*32 + m  ->  j*1024 + g*32 + m   (j = gate r/u/n, m = h-col within group)
static __device__ __forceinline__ int r_orig(int w) {
  const int g = w / 96;
  const int rem = w - g * 96;
  const int j = rem >> 5, m = rem & 31;
  return j * 1024 + g * 32 + m;
}

// ---------------- fragment-major packed layouts ----------------
// A (h, f16 split-2): [row-group][q = k/16][pass hi/lo][64 lanes x 8 u16].
// Lane slot l = ((k>>3)&1)*32 + (row&31) — exactly the mfma_32x32x16 fragment
// order, so ds_read_b128 at base+lane*16 is lane-linear (zero conflicts; verified
// v6: SQ_LDS_BANK_CONFLICT = 0) and global_load_lds staging is linear blocks.
static __device__ __forceinline__ size_t pkA_off(int row, int col) {
  return ((size_t)(row >> 5) * 64 + (col >> 4)) * 1024 +
         (((col >> 3) & 1) * 32 + (row & 31)) * 8 + (col & 7);
}
static __device__ __forceinline__ void pack_writeA(u16* __restrict__ P, int row, int col, float v) {
  const size_t off = pkA_off(row, col);
  const float h = h16_val(v);
  P[off] = h16_bits(v);            // hi pass
  P[off + 512] = h16_bits(v - h);  // lo pass
}
// B (W_hh', f16 single pass): [row-group][q][64 lanes x 8 u16] (512-u16 blocks).
static __device__ __forceinline__ size_t pkB_off(int row, int col) {
  return ((size_t)(row >> 5) * 64 + (col >> 4)) * 512 +
         (((col >> 3) & 1) * 32 + (row & 31)) * 8 + (col & 7);
}

// ---------------- prep kernels ----------------

__global__ void k_split(const float* __restrict__ s, u16* __restrict__ hi,
                        u16* __restrict__ lo, int n) {
  int i = blockIdx.x * 256 + threadIdx.x;
  if (i >= n) return;
  float v = s[i];
  float h = bf_val(v);
  hi[i] = bf_bits(v);
  lo[i] = bf_bits(v - h);
}

// W_hh -> fragment-major single-pass f16 Bpk with gate-interleaved row reorder
__global__ void k_pack_whh(const float* __restrict__ W_hh, u16* __restrict__ Bpk) {
  int i = blockIdx.x * 256 + threadIdx.x;
  if (i >= NP * HIDN) return;
  const int w = i >> 10, k = i & 1023;
  const float v = W_hh[(size_t)r_orig(w) * HIDN + k];
  Bpk[pkB_off(w, k)] = h16_bits(v);
}

// W_ih[:,3:131] -> split (reordered rows); W_ih[:,0:3] -> wtok (reordered); cb0 (reordered)
__global__ void k_prep_wih(const float* __restrict__ W_ih, const float* __restrict__ b_ih,
                           const float* __restrict__ b_hh,
                           u16* __restrict__ whi, u16* __restrict__ wlo,
                           float* __restrict__ wtok, float* __restrict__ cb0) {
  int i = blockIdx.x * 256 + threadIdx.x;
  if (i < NP * 128) {
    const int w = i >> 7, c = i & 127;
    const int r = r_orig(w);
    const float v = W_ih[r * 131 + 3 + c];
    const float h = bf_val(v);
    whi[i] = bf_bits(v);
    wlo[i] = bf_bits(v - h);
  }
  if (i < NP * 3) {
    const int w = i / 3, s = i - w * 3;
    wtok[i] = W_ih[r_orig(w) * 131 + s];
  }
  if (i < NP) {
    const int r = r_orig(i);
    cb0[i] = b_ih[r] + (r < 2048 ? b_hh[r] : 0.0f);
  }
}

__global__ void k_token_init(const float* __restrict__ init_input, float* __restrict__ token) {
  int i = blockIdx.x * 256 + threadIdx.x;
  if (i < BS * 4) token[i] = ((i & 3) < 3) ? init_input[i & 3] : 0.0f;
}

// ---------------- generic split-3 GEMM (prep only): C = A*B^T (+bias) ----------------
// OUTMODE: 0 = f32 only, 1 = f32 + plain hi/lo splits, 2 = f32 + fragment-major f16 Apk
template <int OUTMODE>
__global__ __launch_bounds__(256) void k_gemm(
    const u16* __restrict__ Ahi, const u16* __restrict__ Alo,
    const u16* __restrict__ Bhi, const u16* __restrict__ Blo,
    const float* __restrict__ bias,
    float* __restrict__ C, u16* __restrict__ Chi, u16* __restrict__ Clo,
    u16* __restrict__ Apk, int N, int K) {
  __shared__ __align__(16) u16 sAhi[128 * 64];
  __shared__ __align__(16) u16 sAlo[128 * 64];
  __shared__ __align__(16) u16 sBhi[128 * 64];
  __shared__ __align__(16) u16 sBlo[128 * 64];

  const int t = threadIdx.x;
  const int row0 = blockIdx.y * 128, col0 = blockIdx.x * 128;
  const int wave = t >> 6, lane = t & 63;
  const int w64 = wave * 64;
  const int wm = (wave & 1) * 64, wn = (wave >> 1) * 64;
  const int lm = lane & 15, lq = lane >> 4;
  const int pb = lm & 7;

  f32x4 acc[4][4] = {};

  int sm[4], skc[4], sub[4];
#pragma unroll
  for (int i = 0; i < 4; ++i) {
    const int u = i * 256 + t;
    sm[i] = u >> 3;
    skc[i] = (u & 7) ^ (sm[i] & 7);
    sub[i] = (i * 256 + w64) * 8;
  }

  const int nk = K >> 6;
  for (int kt = 0; kt < nk; ++kt) {
    const int k0 = kt << 6;
    __syncthreads();
#pragma unroll
    for (int i = 0; i < 4; ++i) {
      const size_t ga = (size_t)(row0 + sm[i]) * K + k0 + skc[i] * 8;
      const size_t gb = (size_t)(col0 + sm[i]) * K + k0 + skc[i] * 8;
      ld_lds16(Ahi + ga, &sAhi[sub[i]]);
      ld_lds16(Alo + ga, &sAlo[sub[i]]);
      ld_lds16(Bhi + gb, &sBhi[sub[i]]);
      ld_lds16(Blo + gb, &sBlo[sub[i]]);
    }
    __syncthreads();
#pragma unroll
    for (int kk = 0; kk < 2; ++kk) {
      const int pos = ((kk * 4 + lq) ^ pb) * 8;
      bf16x8 ah[4], al[4], bh[4], bl[4];
#pragma unroll
      for (int i = 0; i < 4; ++i) {
        const int ma = (wm + i * 16 + lm) * 64;
        const int mb = (wn + i * 16 + lm) * 64;
        ah[i] = *(const bf16x8*)&sAhi[ma + pos];
        al[i] = *(const bf16x8*)&sAlo[ma + pos];
        bh[i] = *(const bf16x8*)&sBhi[mb + pos];
        bl[i] = *(const bf16x8*)&sBlo[mb + pos];
      }
#pragma unroll
      for (int i = 0; i < 4; ++i)
#pragma unroll
        for (int j = 0; j < 4; ++j) {
          acc[i][j] = __builtin_amdgcn_mfma_f32_16x16x32_bf16(ah[i], bh[j], acc[i][j], 0, 0, 0);
          acc[i][j] = __builtin_amdgcn_mfma_f32_16x16x32_bf16(al[i], bh[j], acc[i][j], 0, 0, 0);
          acc[i][j] = __builtin_amdgcn_mfma_f32_16x16x32_bf16(ah[i], bl[j], acc[i][j], 0, 0, 0);
        }
    }
  }

#pragma unroll
  for (int i = 0; i < 4; ++i) {
    const int grow = row0 + wm + i * 16 + lq * 4;
#pragma unroll
    for (int j = 0; j < 4; ++j) {
      const int gcol = col0 + wn + j * 16 + lm;
      const float bs = bias ? bias[gcol] : 0.0f;
#pragma unroll
      for (int d = 0; d < 4; ++d) {
        const float v = acc[i][j][d] + bs;
        const size_t idx = (size_t)(grow + d) * N + gcol;
        C[idx] = v;
        if (OUTMODE == 1) {
          const float h = bf_val(v);
          Chi[idx] = bf_bits(v);
          Clo[idx] = bf_bits(v - h);
        }
        if (OUTMODE == 2) {
          pack_writeA(Apk, grow + d, gcol, v);
        }
      }
    }
  }
}

// ---------------- fused gh-GEMM + GRU gate kernel (v7: f16 split-2, -33% work) ----------------
// v6 skeleton unchanged (128M x 192N', BK=32 dbuf, 2 blk/CU, 8 waves 4Mx2N, one
// __syncthreads per K-tile, lane-linear fragment-major LDS -> 0 bank conflicts).
// Work reduction: A = f16 hi+lo (22-bit mantissa), B = single f16 (11-bit); both
// passes accumulate into the SAME f32 acc. Per wave per tile: 12 MFMA (was 18),
// 10 ds_read_b128 (was 16), 28 KB staging (was 40). LDS 56 KB total.

#define SZA7 (128 * 64)   // 8192 u16 per buf: [4 g][2 q][2 pass][512]
#define SZB7 (192 * 32)   // 6144 u16 per buf: [12 id][512]
#define MF7(a, b, c) c = __builtin_amdgcn_mfma_f32_32x32x16_f16(a, b, c, 0, 0, 0)

__global__ __launch_bounds__(512, 4) void k_fused7(
    const u16* __restrict__ Apk,   // f16 frag-major h splits [128 rg][64 q][2 pass][512]
    const u16* __restrict__ Bpk,   // f16 frag-major Whh'     [96 rg][64 q][512]
    const float* __restrict__ C0,  // [4096][3072] W'-order
    const float* __restrict__ token,
    const float* __restrict__ wtok,
    const float* __restrict__ b_hh,
    const float* __restrict__ h_in, float* __restrict__ h_out,
    u16* __restrict__ Apk_out) {
  __shared__ __align__(16) u16 sA[2 * SZA7];
  __shared__ __align__(16) u16 sB[2 * SZB7];

  const int t = threadIdx.x;
  const int wave = t >> 6, lane = t & 63;
  const int row0 = blockIdx.y * 128;
  const int colW0 = blockIdx.x * 192;
  const int wm = (wave >> 1) * 32;   // 4 M-waves x 32 rows
  const int wn = (wave & 1) * 96;    // 2 N-waves x 96 W-rows (one gate-triple group)
  const int lr = lane & 31, lh = lane >> 5;

  f32x16 acc0 = {}, acc1 = {}, acc2 = {};

  // ---- staging: 16 A pass-blocks + 12 B blocks per tile ----
  // A: wave w stages (g = w>>1, q = w&1), both passes (2 gloads).
  const u16* asrc = Apk + ((size_t)((row0 >> 5) + (wave >> 1)) * 64 + (wave & 1)) * 1024 + lane * 8;
  const int aw = (wave >> 1) * 2048 + (wave & 1) * 1024;
  // B: id = g*2+q; wave stages id0 = wave; waves 0-3 also stage id1 = 8+wave.
  const int id0 = wave, id1 = 8 + wave;
  const u16* bsrc0 = Bpk + ((size_t)((colW0 >> 5) + (id0 >> 1)) * 64 + (id0 & 1)) * 512 + lane * 8;
  const u16* bsrc1 = Bpk + ((size_t)((colW0 >> 5) + ((id1 >> 1) % 6)) * 64 + (id1 & 1)) * 512 + lane * 8;
  const int bw0 = id0 * 512, bw1 = (id1 % 12) * 512;
  const bool two_b = (wave < 4);

#define STAGE(kt_, ab, bb)                                            \
  ld_lds16(asrc + (size_t)(kt_) * 2048,       &sA[(ab) + aw]);        \
  ld_lds16(asrc + (size_t)(kt_) * 2048 + 512, &sA[(ab) + aw + 512]);  \
  ld_lds16(bsrc0 + (size_t)(kt_) * 1024, &sB[(bb) + bw0]);            \
  if (two_b) { ld_lds16(bsrc1 + (size_t)(kt_) * 1024, &sB[(bb) + bw1]); }

  // ---- fragment read bases (lane-linear) ----
  const int agA = (wave >> 1) * 2048;    // + kk*1024; hi at +0, lo at +512
  const int bgB = (wave & 1) * 3072;     // + j*1024 + kk*512
  const int l8 = lane * 8;

  STAGE(0, 0, 0);
  __syncthreads();

#pragma unroll 1
  for (int kt = 0; kt < 32; ++kt) {
    const int ab = (kt & 1) ? SZA7 : 0, bb = (kt & 1) ? SZB7 : 0;
    const int an = (kt & 1) ? 0 : SZA7, bn = (kt & 1) ? 0 : SZB7;
    if (kt < 31) { STAGE(kt + 1, an, bn); }
#pragma unroll
    for (int kk = 0; kk < 2; ++kk) {
      const int ka = ab + agA + kk * 1024 + l8;
      const f16x8 ah = *(const f16x8*)&sA[ka];
      const f16x8 al = *(const f16x8*)&sA[ka + 512];
      const int kb = bb + bgB + kk * 512 + l8;
      const f16x8 b0 = *(const f16x8*)&sB[kb];
      const f16x8 b1 = *(const f16x8*)&sB[kb + 1024];
      const f16x8 b2 = *(const f16x8*)&sB[kb + 2048];
      MF7(ah, b0, acc0); MF7(ah, b1, acc1); MF7(ah, b2, acc2);
      MF7(al, b0, acc0); MF7(al, b1, acc1); MF7(al, b2, acc2);
    }
    __syncthreads();
  }
#undef STAGE

  // ---- fused GRU epilogue (exact f32) ----
  const int w0 = colW0 + wn + lr;                  // W'-row of r-gate
  const int c = ((colW0 + wn) / 96) * 32 + lr;     // h-col
  float wt[3][3];
#pragma unroll
  for (int j = 0; j < 3; ++j) {
    wt[j][0] = wtok[(w0 + j * 32) * 3 + 0];
    wt[j][1] = wtok[(w0 + j * 32) * 3 + 1];
    wt[j][2] = wtok[(w0 + j * 32) * 3 + 2];
  }
  const float bn = b_hh[2048 + c];
  const int cq = c >> 4, ckh = (c >> 3) & 1, ce = c & 7;
#pragma unroll
  for (int d = 0; d < 16; ++d) {
    const int row = row0 + wm + 4 * lh + (d & 3) + 8 * (d >> 2);
    const float4 tk = *(const float4*)&token[row * 4];
    const size_t cb = (size_t)row * NP;
    const float pr = C0[cb + w0]      + acc0[d] + tk.x * wt[0][0] + tk.y * wt[0][1] + tk.z * wt[0][2];
    const float pu = C0[cb + w0 + 32] + acc1[d] + tk.x * wt[1][0] + tk.y * wt[1][1] + tk.z * wt[1][2];
    const float pn = C0[cb + w0 + 64] + tk.x * wt[2][0] + tk.y * wt[2][1] + tk.z * wt[2][2];
    const float hn = acc2[d] + bn;
    const float r = 1.0f / (1.0f + expf(-pr));
    const float u = 1.0f / (1.0f + expf(-pu));
    const float n = tanhf(pn + r * hn);
    const size_t hidx = (size_t)row * HIDN + c;
    const float hv = (1.0f - u) * n + u * h_in[hidx];
    h_out[hidx] = hv;
    const size_t poff = ((size_t)(row >> 5) * 64 + cq) * 1024 + (ckh * 32 + (row & 31)) * 8 + ce;
    const float hh = h16_val(hv);
    Apk_out[poff] = h16_bits(hv);
    Apk_out[poff + 512] = h16_bits(hv - hh);
  }
}
#undef MF7

// ---------------- per-step output kernel ----------------
__global__ __launch_bounds__(256) void k_out(
    const float* __restrict__ h, const float* __restrict__ W_out,
    const float* __restrict__ b_out,
    float* __restrict__ out, float* __restrict__ token, int step) {
  const int wave = threadIdx.x >> 6, lane = threadIdx.x & 63;
  const int row = blockIdx.x * 4 + wave;
  const float4* hp = (const float4*)(h + (size_t)row * 1024);
  const float4* w0p = (const float4*)(W_out);
  const float4* w1p = (const float4*)(W_out + 1024);
  const float4* w2p = (const float4*)(W_out + 2048);
  float s0 = 0.f, s1 = 0.f, s2 = 0.f;
#pragma unroll
  for (int c = 0; c < 4; ++c) {
    const int k = lane + 64 * c;
    const float4 hv = hp[k];
    const float4 a = w0p[k], bq = w1p[k], cq = w2p[k];
    s0 += hv.x * a.x + hv.y * a.y + hv.z * a.z + hv.w * a.w;
    s1 += hv.x * bq.x + hv.y * bq.y + hv.z * bq.z + hv.w * bq.w;
    s2 += hv.x * cq.x + hv.y * cq.y + hv.z * cq.z + hv.w * cq.w;
  }
#pragma unroll
  for (int off = 32; off > 0; off >>= 1) {
    s0 += __shfl_xor(s0, off, 64);
    s1 += __shfl_xor(s1, off, 64);
    s2 += __shfl_xor(s2, off, 64);
  }
  if (lane == 0) {
    const float o0 = s0 + b_out[0];
    const float o1 = s1 + b_out[1];
    const float o2 = s2 + b_out[2];
    const float bass = 1.0f / (1.0f + expf(-o0));
    const float rhy = 1.0f / (1.0f + expf(-o2));
    const size_t ob = ((size_t)row * NST + step) * 3;
    out[ob + 0] = bass;
    out[ob + 1] = o1;
    out[ob + 2] = rhy;
    token[row * 4 + 0] = bass;
    token[row * 4 + 1] = o1;
    token[row * 4 + 2] = (rhy > 0.5f) ? 1.0f : 0.0f;
  }
}

// ---------------- host ----------------
extern "C" void kernel_launch(void* const* d_in, const int* in_sizes, int n_in,
                              void* d_out, int out_size, void* d_ws, size_t ws_size,
                              hipStream_t stream) {
  const float* z = (const float*)d_in[0];
  const float* W_zh = (const float*)d_in[3];
  const float* b_zh = (const float*)d_in[4];
  const float* W_zi = (const float*)d_in[5];
  const float* b_zi = (const float*)d_in[6];
  const float* W_ih = (const float*)d_in[7];
  const float* b_ih = (const float*)d_in[8];
  const float* W_hh = (const float*)d_in[9];
  const float* b_hh = (const float*)d_in[10];
  const float* W_out = (const float*)d_in[11];
  const float* b_out = (const float*)d_in[12];
  const float* init_input = (const float*)d_in[13];
  float* out = (float*)d_out;

  char* p = (char*)d_ws;
  auto alloc = [&](size_t bytes) {
    char* q = p;
    p += (bytes + 255) & ~(size_t)255;
    return q;
  };
  float* h[2];
  u16* Apk[2];
  for (int s = 0; s < 2; ++s) {
    h[s] = (float*)alloc((size_t)BS * HIDN * 4);
    Apk[s] = (u16*)alloc((size_t)BS * 2048 * 2);
  }
  float* C0 = (float*)alloc((size_t)BS * NP * 4);
  u16* z_hi = (u16*)alloc((size_t)BS * ZD * 2);
  u16* z_lo = (u16*)alloc((size_t)BS * ZD * 2);
  float* zin = (float*)alloc((size_t)BS * ZINN * 4);
  u16* zin_hi = (u16*)alloc((size_t)BS * ZINN * 2);
  u16* zin_lo = (u16*)alloc((size_t)BS * ZINN * 2);
  u16* Wzh_hi = (u16*)alloc((size_t)HIDN * ZD * 2);
  u16* Wzh_lo = (u16*)alloc((size_t)HIDN * ZD * 2);
  u16* Wzi_hi = (u16*)alloc((size_t)ZINN * ZD * 2);
  u16* Wzi_lo = (u16*)alloc((size_t)ZINN * ZD * 2);
  u16* Wihz_hi = (u16*)alloc((size_t)NP * ZINN * 2);
  u16* Wihz_lo = (u16*)alloc((size_t)NP * ZINN * 2);
  u16* Bpk = (u16*)alloc((size_t)NP * 1024 * 2);   // single f16 pass
  float* wtok = (float*)alloc((size_t)NP * 3 * 4);
  float* cb0 = (float*)alloc((size_t)NP * 4);
  float* token = (float*)alloc((size_t)BS * 4 * 4);

  // ---- prep ----
  k_pack_whh<<<dim3((NP * HIDN + 255) / 256), 256, 0, stream>>>(W_hh, Bpk);
  k_split<<<dim3((HIDN * ZD + 255) / 256), 256, 0, stream>>>(W_zh, Wzh_hi, Wzh_lo, HIDN * ZD);
  k_split<<<dim3((ZINN * ZD + 255) / 256), 256, 0, stream>>>(W_zi, Wzi_hi, Wzi_lo, ZINN * ZD);
  k_split<<<dim3((BS * ZD + 255) / 256), 256, 0, stream>>>(z, z_hi, z_lo, BS * ZD);
  k_prep_wih<<<dim3((NP * 128 + 255) / 256), 256, 0, stream>>>(W_ih, b_ih, b_hh, Wihz_hi, Wihz_lo, wtok, cb0);
  k_token_init<<<dim3((BS * 4 + 255) / 256), 256, 0, stream>>>(init_input, token);

  // ---- prep GEMMs ----
  k_gemm<2><<<dim3(HIDN / 128, BS / 128), 256, 0, stream>>>(
      z_hi, z_lo, Wzh_hi, Wzh_lo, b_zh, h[0], nullptr, nullptr, Apk[0], HIDN, ZD);
  k_gemm<1><<<dim3(ZINN / 128, BS / 128), 256, 0, stream>>>(
      z_hi, z_lo, Wzi_hi, Wzi_lo, b_zi, zin, zin_hi, zin_lo, nullptr, ZINN, ZD);
  k_gemm<0><<<dim3(NP / 128, BS / 128), 256, 0, stream>>>(
      zin_hi, zin_lo, Wihz_hi, Wihz_lo, cb0, C0, nullptr, nullptr, nullptr, NP, ZINN);

  // ---- 32 recurrent steps ----
  for (int t = 0; t < NST; ++t) {
    const int cur = t & 1, nxt = (t + 1) & 1;
    k_fused7<<<dim3(NP / 192, BS / 128), 512, 0, stream>>>(
        Apk[cur], Bpk, C0, token, wtok, b_hh, h[cur], h[nxt], Apk[nxt]);
    k_out<<<dim3(BS / 4), 256, 0, stream>>>(h[nxt], W_out, b_out, out, token, t);
  }
  (void)in_sizes; (void)n_in; (void)out_size; (void)ws_size;
}

// Round 8
// 1743.113 us; speedup vs baseline: 1.6633x; 1.3399x over previous
//
#include <hip/hip_runtime.h>
#include <hip/hip_bf16.h>
#include <math.h>

#define BS   4096
#define ZD   512
#define HIDN 1024
#define ZINN 128
#define NST  32
#define NP   3072   // 3*HIDN, gate-interleaved column space (96 = 3x32 groups)

typedef unsigned short u16;
typedef __bf16 bf16x8 __attribute__((ext_vector_type(8)));
typedef _Float16 f16x8 __attribute__((ext_vector_type(8)));
typedef float f32x4 __attribute__((ext_vector_type(4)));
typedef float f32x16 __attribute__((ext_vector_type(16)));

static __device__ __forceinline__ u16 bf_bits(float v) {
  __bf16 b = (__bf16)v;
  return __builtin_bit_cast(unsigned short, b);
}
static __device__ __forceinline__ float bf_val(float v) {
  return (float)(__bf16)v;
}
static __device__ __forceinline__ u16 h16_bits(float v) {
  _Float16 h = (_Float16)v;
  return __builtin_bit_cast(unsigned short, h);
}

// async global -> LDS, 16 bytes per lane. LDS dest = wave-uniform base + lane*16.
static __device__ __forceinline__ void ld_lds16(const u16* g, u16* l) {
  __builtin_amdgcn_global_load_lds(
      (const __attribute__((address_space(1))) void*)g,
      (__attribute__((address_space(3))) void*)l, 16, 0, 0);
}

// W' row w -> original W_hh/W_ih row. 32-granular interleave for 32x32 MFMA:
// w = g*96 + j*32 + m  ->  j*1024 + g*32 + m   (j = gate r/u/n, m = h-col within group)
static __device__ __forceinline__ int r_orig(int w) {
  const int g = w / 96;
  const int rem = w - g * 96;
  const int j = rem >> 5, m = rem & 31;
  return j * 1024 + g * 32 + m;
}

// ---------------- fragment-major packed layout (single f16 pass) ----------------
// Pk: [row-group (rows/32)][q = k/16][64 lanes x 8 u16] (512-u16 = 1KB blocks).
// Lane slot l = ((k>>3)&1)*32 + (row&31) — exactly the mfma_32x32x16 fragment
// order, so ds_read_b128 at base+lane*16 is lane-linear (0 conflicts; verified v6/v7)
// and global_load_lds staging is linear blocks (global block order == LDS order).
static __device__ __forceinline__ size_t pk_off(int row, int col) {
  return ((size_t)(row >> 5) * 64 + (col >> 4)) * 512 +
         (((col >> 3) & 1) * 32 + (row & 31)) * 8 + (col & 7);
}

// ---------------- prep kernels ----------------

__global__ void k_split(const float* __restrict__ s, u16* __restrict__ hi,
                        u16* __restrict__ lo, int n) {
  int i = blockIdx.x * 256 + threadIdx.x;
  if (i >= n) return;
  float v = s[i];
  float h = bf_val(v);
  hi[i] = bf_bits(v);
  lo[i] = bf_bits(v - h);
}

// W_hh -> fragment-major single-pass f16 Bpk with gate-interleaved row reorder
__global__ void k_pack_whh(const float* __restrict__ W_hh, u16* __restrict__ Bpk) {
  int i = blockIdx.x * 256 + threadIdx.x;
  if (i >= NP * HIDN) return;
  const int w = i >> 10, k = i & 1023;
  const float v = W_hh[(size_t)r_orig(w) * HIDN + k];
  Bpk[pk_off(w, k)] = h16_bits(v);
}

// W_ih[:,3:131] -> split (reordered rows); W_ih[:,0:3] -> wtok (reordered); cb0 (reordered)
__global__ void k_prep_wih(const float* __restrict__ W_ih, const float* __restrict__ b_ih,
                           const float* __restrict__ b_hh,
                           u16* __restrict__ whi, u16* __restrict__ wlo,
                           float* __restrict__ wtok, float* __restrict__ cb0) {
  int i = blockIdx.x * 256 + threadIdx.x;
  if (i < NP * 128) {
    const int w = i >> 7, c = i & 127;
    const int r = r_orig(w);
    const float v = W_ih[r * 131 + 3 + c];
    const float h = bf_val(v);
    whi[i] = bf_bits(v);
    wlo[i] = bf_bits(v - h);
  }
  if (i < NP * 3) {
    const int w = i / 3, s = i - w * 3;
    wtok[i] = W_ih[r_orig(w) * 131 + s];
  }
  if (i < NP) {
    const int r = r_orig(i);
    cb0[i] = b_ih[r] + (r < 2048 ? b_hh[r] : 0.0f);
  }
}

__global__ void k_token_init(const float* __restrict__ init_input, float* __restrict__ token) {
  int i = blockIdx.x * 256 + threadIdx.x;
  if (i < BS * 4) token[i] = ((i & 3) < 3) ? init_input[i & 3] : 0.0f;
}

// ---------------- generic split-3 GEMM (prep only): C = A*B^T (+bias) ----------------
// OUTMODE: 0 = f32 only, 1 = f32 + plain hi/lo splits, 2 = f32 + fragment-major f16 Apk
template <int OUTMODE>
__global__ __launch_bounds__(256) void k_gemm(
    const u16* __restrict__ Ahi, const u16* __restrict__ Alo,
    const u16* __restrict__ Bhi, const u16* __restrict__ Blo,
    const float* __restrict__ bias,
    float* __restrict__ C, u16* __restrict__ Chi, u16* __restrict__ Clo,
    u16* __restrict__ Apk, int N, int K) {
  __shared__ __align__(16) u16 sAhi[128 * 64];
  __shared__ __align__(16) u16 sAlo[128 * 64];
  __shared__ __align__(16) u16 sBhi[128 * 64];
  __shared__ __align__(16) u16 sBlo[128 * 64];

  const int t = threadIdx.x;
  const int row0 = blockIdx.y * 128, col0 = blockIdx.x * 128;
  const int wave = t >> 6, lane = t & 63;
  const int w64 = wave * 64;
  const int wm = (wave & 1) * 64, wn = (wave >> 1) * 64;
  const int lm = lane & 15, lq = lane >> 4;
  const int pb = lm & 7;

  f32x4 acc[4][4] = {};

  int sm[4], skc[4], sub[4];
#pragma unroll
  for (int i = 0; i < 4; ++i) {
    const int u = i * 256 + t;
    sm[i] = u >> 3;
    skc[i] = (u & 7) ^ (sm[i] & 7);
    sub[i] = (i * 256 + w64) * 8;
  }

  const int nk = K >> 6;
  for (int kt = 0; kt < nk; ++kt) {
    const int k0 = kt << 6;
    __syncthreads();
#pragma unroll
    for (int i = 0; i < 4; ++i) {
      const size_t ga = (size_t)(row0 + sm[i]) * K + k0 + skc[i] * 8;
      const size_t gb = (size_t)(col0 + sm[i]) * K + k0 + skc[i] * 8;
      ld_lds16(Ahi + ga, &sAhi[sub[i]]);
      ld_lds16(Alo + ga, &sAlo[sub[i]]);
      ld_lds16(Bhi + gb, &sBhi[sub[i]]);
      ld_lds16(Blo + gb, &sBlo[sub[i]]);
    }
    __syncthreads();
#pragma unroll
    for (int kk = 0; kk < 2; ++kk) {
      const int pos = ((kk * 4 + lq) ^ pb) * 8;
      bf16x8 ah[4], al[4], bh[4], bl[4];
#pragma unroll
      for (int i = 0; i < 4; ++i) {
        const int ma = (wm + i * 16 + lm) * 64;
        const int mb = (wn + i * 16 + lm) * 64;
        ah[i] = *(const bf16x8*)&sAhi[ma + pos];
        al[i] = *(const bf16x8*)&sAlo[ma + pos];
        bh[i] = *(const bf16x8*)&sBhi[mb + pos];
        bl[i] = *(const bf16x8*)&sBlo[mb + pos];
      }
#pragma unroll
      for (int i = 0; i < 4; ++i)
#pragma unroll
        for (int j = 0; j < 4; ++j) {
          acc[i][j] = __builtin_amdgcn_mfma_f32_16x16x32_bf16(ah[i], bh[j], acc[i][j], 0, 0, 0);
          acc[i][j] = __builtin_amdgcn_mfma_f32_16x16x32_bf16(al[i], bh[j], acc[i][j], 0, 0, 0);
          acc[i][j] = __builtin_amdgcn_mfma_f32_16x16x32_bf16(ah[i], bl[j], acc[i][j], 0, 0, 0);
        }
    }
  }

#pragma unroll
  for (int i = 0; i < 4; ++i) {
    const int grow = row0 + wm + i * 16 + lq * 4;
#pragma unroll
    for (int j = 0; j < 4; ++j) {
      const int gcol = col0 + wn + j * 16 + lm;
      const float bs = bias ? bias[gcol] : 0.0f;
#pragma unroll
      for (int d = 0; d < 4; ++d) {
        const float v = acc[i][j][d] + bs;
        const size_t idx = (size_t)(grow + d) * N + gcol;
        C[idx] = v;
        if (OUTMODE == 1) {
          const float h = bf_val(v);
          Chi[idx] = bf_bits(v);
          Clo[idx] = bf_bits(v - h);
        }
        if (OUTMODE == 2) {
          Apk[pk_off(grow + d, gcol)] = h16_bits(v);
        }
      }
    }
  }
}

// ---------------- fused gh-GEMM + GRU gate kernel (v8: f16 single-pass + BK=64) ----------------
// v7 skeleton; two changes on the validated work-reduction lever:
//  (1) A single f16 pass (lo-pass dropped — its error term is 5x below B's accepted
//      f16 rounding): 6 MFMA + 8 ds_read_b128 per wave per BK-tile-equivalent.
//  (2) BK=64: 16 K-tiles instead of 32 — halves the count of ~2500-cyc
//      barrier/drain overhead events. LDS = (16+24)KB x 2 = exactly 80KB -> 2 blk/CU.
// Same hazard structure (STAGE(kt+1, other-buf) at top, one __syncthreads per tile);
// lane-linear fragment-major LDS (0 bank conflicts, verified v6/v7).

#define SZA8 (128 * 64)   // 8192 u16/buf: [4 rg][4 q][512]
#define SZB8 (192 * 64)   // 12288 u16/buf: [6 rg][4 q][512]
#define MF8(a, b, c) c = __builtin_amdgcn_mfma_f32_32x32x16_f16(a, b, c, 0, 0, 0)

__global__ __launch_bounds__(512, 4) void k_fused8(
    const u16* __restrict__ Apk,   // f16 frag-major h [128 rg][64 q][512]
    const u16* __restrict__ Bpk,   // f16 frag-major Whh' [96 rg][64 q][512]
    const float* __restrict__ C0,  // [4096][3072] W'-order
    const float* __restrict__ token,
    const float* __restrict__ wtok,
    const float* __restrict__ b_hh,
    const float* __restrict__ h_in, float* __restrict__ h_out,
    u16* __restrict__ Apk_out) {
  __shared__ __align__(16) u16 sA[2 * SZA8];
  __shared__ __align__(16) u16 sB[2 * SZB8];

  const int t = threadIdx.x;
  const int wave = t >> 6, lane = t & 63;
  const int row0 = blockIdx.y * 128;
  const int colW0 = blockIdx.x * 192;
  const int wm = (wave >> 1) * 32;   // 4 M-waves x 32 rows
  const int wn = (wave & 1) * 96;    // 2 N-waves x 96 W-rows (one gate-triple group)
  const int lr = lane & 31, lh = lane >> 5;

  f32x16 acc0 = {}, acc1 = {}, acc2 = {};

  // ---- staging: 16 A blocks + 24 B blocks per BK=64 tile, 5 loads/wave ----
  // A: wave w stages (rg = w>>1, q = (w&1)*2 + p), p = 0,1.
  const u16* asrc = Apk + ((size_t)((row0 >> 5) + (wave >> 1)) * 64 + (wave & 1) * 2) * 512 + lane * 8;
  const int aw = (wave >> 1) * 2048 + (wave & 1) * 1024;
  // B: id = wave*3 + j -> (rg = id>>2, q = id&3); LDS slot = id*512.
  const int id0 = wave * 3, id1 = id0 + 1, id2 = id0 + 2;
  const u16* bsrc0 = Bpk + ((size_t)((colW0 >> 5) + (id0 >> 2)) * 64 + (id0 & 3)) * 512 + lane * 8;
  const u16* bsrc1 = Bpk + ((size_t)((colW0 >> 5) + (id1 >> 2)) * 64 + (id1 & 3)) * 512 + lane * 8;
  const u16* bsrc2 = Bpk + ((size_t)((colW0 >> 5) + (id2 >> 2)) * 64 + (id2 & 3)) * 512 + lane * 8;
  const int bw0 = id0 * 512, bw1 = id1 * 512, bw2 = id2 * 512;

#define STAGE(kt_, ab, bb)                                            \
  ld_lds16(asrc + (size_t)(kt_) * 2048,       &sA[(ab) + aw]);        \
  ld_lds16(asrc + (size_t)(kt_) * 2048 + 512, &sA[(ab) + aw + 512]);  \
  ld_lds16(bsrc0 + (size_t)(kt_) * 2048, &sB[(bb) + bw0]);            \
  ld_lds16(bsrc1 + (size_t)(kt_) * 2048, &sB[(bb) + bw1]);            \
  ld_lds16(bsrc2 + (size_t)(kt_) * 2048, &sB[(bb) + bw2]);

  // ---- fragment read bases (lane-linear) ----
  const int agA = (wave >> 1) * 2048;    // + kk*512
  const int bgB = (wave & 1) * 6144;     // + j*2048 + kk*512
  const int l8 = lane * 8;

  STAGE(0, 0, 0);
  __syncthreads();

#pragma unroll 1
  for (int kt = 0; kt < 16; ++kt) {
    const int ab = (kt & 1) ? SZA8 : 0, bb = (kt & 1) ? SZB8 : 0;
    const int an = (kt & 1) ? 0 : SZA8, bn = (kt & 1) ? 0 : SZB8;
    if (kt < 15) { STAGE(kt + 1, an, bn); }
#pragma unroll
    for (int kk = 0; kk < 4; ++kk) {
      const f16x8 a = *(const f16x8*)&sA[ab + agA + kk * 512 + l8];
      const int kb = bb + bgB + kk * 512 + l8;
      const f16x8 b0 = *(const f16x8*)&sB[kb];
      const f16x8 b1 = *(const f16x8*)&sB[kb + 2048];
      const f16x8 b2 = *(const f16x8*)&sB[kb + 4096];
      MF8(a, b0, acc0); MF8(a, b1, acc1); MF8(a, b2, acc2);
    }
    __syncthreads();
  }
#undef STAGE

  // ---- fused GRU epilogue (exact f32) ----
  const int w0 = colW0 + wn + lr;                  // W'-row of r-gate
  const int c = ((colW0 + wn) / 96) * 32 + lr;     // h-col
  float wt[3][3];
#pragma unroll
  for (int j = 0; j < 3; ++j) {
    wt[j][0] = wtok[(w0 + j * 32) * 3 + 0];
    wt[j][1] = wtok[(w0 + j * 32) * 3 + 1];
    wt[j][2] = wtok[(w0 + j * 32) * 3 + 2];
  }
  const float bn = b_hh[2048 + c];
  const int cq = c >> 4, ckh = (c >> 3) & 1, ce = c & 7;
#pragma unroll
  for (int d = 0; d < 16; ++d) {
    const int row = row0 + wm + 4 * lh + (d & 3) + 8 * (d >> 2);
    const float4 tk = *(const float4*)&token[row * 4];
    const size_t cb = (size_t)row * NP;
    const float pr = C0[cb + w0]      + acc0[d] + tk.x * wt[0][0] + tk.y * wt[0][1] + tk.z * wt[0][2];
    const float pu = C0[cb + w0 + 32] + acc1[d] + tk.x * wt[1][0] + tk.y * wt[1][1] + tk.z * wt[1][2];
    const float pn = C0[cb + w0 + 64] + tk.x * wt[2][0] + tk.y * wt[2][1] + tk.z * wt[2][2];
    const float hn = acc2[d] + bn;
    const float r = 1.0f / (1.0f + expf(-pr));
    const float u = 1.0f / (1.0f + expf(-pu));
    const float n = tanhf(pn + r * hn);
    const size_t hidx = (size_t)row * HIDN + c;
    const float hv = (1.0f - u) * n + u * h_in[hidx];
    h_out[hidx] = hv;
    const size_t poff = ((size_t)(row >> 5) * 64 + cq) * 512 + (ckh * 32 + (row & 31)) * 8 + ce;
    Apk_out[poff] = h16_bits(hv);
  }
}
#undef MF8

// ---------------- per-step output kernel ----------------
__global__ __launch_bounds__(256) void k_out(
    const float* __restrict__ h, const float* __restrict__ W_out,
    const float* __restrict__ b_out,
    float* __restrict__ out, float* __restrict__ token, int step) {
  const int wave = threadIdx.x >> 6, lane = threadIdx.x & 63;
  const int row = blockIdx.x * 4 + wave;
  const float4* hp = (const float4*)(h + (size_t)row * 1024);
  const float4* w0p = (const float4*)(W_out);
  const float4* w1p = (const float4*)(W_out + 1024);
  const float4* w2p = (const float4*)(W_out + 2048);
  float s0 = 0.f, s1 = 0.f, s2 = 0.f;
#pragma unroll
  for (int c = 0; c < 4; ++c) {
    const int k = lane + 64 * c;
    const float4 hv = hp[k];
    const float4 a = w0p[k], bq = w1p[k], cq = w2p[k];
    s0 += hv.x * a.x + hv.y * a.y + hv.z * a.z + hv.w * a.w;
    s1 += hv.x * bq.x + hv.y * bq.y + hv.z * bq.z + hv.w * bq.w;
    s2 += hv.x * cq.x + hv.y * cq.y + hv.z * cq.z + hv.w * cq.w;
  }
#pragma unroll
  for (int off = 32; off > 0; off >>= 1) {
    s0 += __shfl_xor(s0, off, 64);
    s1 += __shfl_xor(s1, off, 64);
    s2 += __shfl_xor(s2, off, 64);
  }
  if (lane == 0) {
    const float o0 = s0 + b_out[0];
    const float o1 = s1 + b_out[1];
    const float o2 = s2 + b_out[2];
    const float bass = 1.0f / (1.0f + expf(-o0));
    const float rhy = 1.0f / (1.0f + expf(-o2));
    const size_t ob = ((size_t)row * NST + step) * 3;
    out[ob + 0] = bass;
    out[ob + 1] = o1;
    out[ob + 2] = rhy;
    token[row * 4 + 0] = bass;
    token[row * 4 + 1] = o1;
    token[row * 4 + 2] = (rhy > 0.5f) ? 1.0f : 0.0f;
  }
}

// ---------------- host ----------------
extern "C" void kernel_launch(void* const* d_in, const int* in_sizes, int n_in,
                              void* d_out, int out_size, void* d_ws, size_t ws_size,
                              hipStream_t stream) {
  const float* z = (const float*)d_in[0];
  const float* W_zh = (const float*)d_in[3];
  const float* b_zh = (const float*)d_in[4];
  const float* W_zi = (const float*)d_in[5];
  const float* b_zi = (const float*)d_in[6];
  const float* W_ih = (const float*)d_in[7];
  const float* b_ih = (const float*)d_in[8];
  const float* W_hh = (const float*)d_in[9];
  const float* b_hh = (const float*)d_in[10];
  const float* W_out = (const float*)d_in[11];
  const float* b_out = (const float*)d_in[12];
  const float* init_input = (const float*)d_in[13];
  float* out = (float*)d_out;

  char* p = (char*)d_ws;
  auto alloc = [&](size_t bytes) {
    char* q = p;
    p += (bytes + 255) & ~(size_t)255;
    return q;
  };
  float* h[2];
  u16* Apk[2];
  for (int s = 0; s < 2; ++s) {
    h[s] = (float*)alloc((size_t)BS * HIDN * 4);
    Apk[s] = (u16*)alloc((size_t)BS * 1024 * 2);   // single f16 pass
  }
  float* C0 = (float*)alloc((size_t)BS * NP * 4);
  u16* z_hi = (u16*)alloc((size_t)BS * ZD * 2);
  u16* z_lo = (u16*)alloc((size_t)BS * ZD * 2);
  float* zin = (float*)alloc((size_t)BS * ZINN * 4);
  u16* zin_hi = (u16*)alloc((size_t)BS * ZINN * 2);
  u16* zin_lo = (u16*)alloc((size_t)BS * ZINN * 2);
  u16* Wzh_hi = (u16*)alloc((size_t)HIDN * ZD * 2);
  u16* Wzh_lo = (u16*)alloc((size_t)HIDN * ZD * 2);
  u16* Wzi_hi = (u16*)alloc((size_t)ZINN * ZD * 2);
  u16* Wzi_lo = (u16*)alloc((size_t)ZINN * ZD * 2);
  u16* Wihz_hi = (u16*)alloc((size_t)NP * ZINN * 2);
  u16* Wihz_lo = (u16*)alloc((size_t)NP * ZINN * 2);
  u16* Bpk = (u16*)alloc((size_t)NP * 1024 * 2);   // single f16 pass
  float* wtok = (float*)alloc((size_t)NP * 3 * 4);
  float* cb0 = (float*)alloc((size_t)NP * 4);
  float* token = (float*)alloc((size_t)BS * 4 * 4);

  // ---- prep ----
  k_pack_whh<<<dim3((NP * HIDN + 255) / 256), 256, 0, stream>>>(W_hh, Bpk);
  k_split<<<dim3((HIDN * ZD + 255) / 256), 256, 0, stream>>>(W_zh, Wzh_hi, Wzh_lo, HIDN * ZD);
  k_split<<<dim3((ZINN * ZD + 255) / 256), 256, 0, stream>>>(W_zi, Wzi_hi, Wzi_lo, ZINN * ZD);
  k_split<<<dim3((BS * ZD + 255) / 256), 256, 0, stream>>>(z, z_hi, z_lo, BS * ZD);
  k_prep_wih<<<dim3((NP * 128 + 255) / 256), 256, 0, stream>>>(W_ih, b_ih, b_hh, Wihz_hi, Wihz_lo, wtok, cb0);
  k_token_init<<<dim3((BS * 4 + 255) / 256), 256, 0, stream>>>(init_input, token);

  // ---- prep GEMMs ----
  k_gemm<2><<<dim3(HIDN / 128, BS / 128), 256, 0, stream>>>(
      z_hi, z_lo, Wzh_hi, Wzh_lo, b_zh, h[0], nullptr, nullptr, Apk[0], HIDN, ZD);
  k_gemm<1><<<dim3(ZINN / 128, BS / 128), 256, 0, stream>>>(
      z_hi, z_lo, Wzi_hi, Wzi_lo, b_zi, zin, zin_hi, zin_lo, nullptr, ZINN, ZD);
  k_gemm<0><<<dim3(NP / 128, BS / 128), 256, 0, stream>>>(
      zin_hi, zin_lo, Wihz_hi, Wihz_lo, cb0, C0, nullptr, nullptr, nullptr, NP, ZINN);

  // ---- 32 recurrent steps ----
  for (int t = 0; t < NST; ++t) {
    const int cur = t & 1, nxt = (t + 1) & 1;
    k_fused8<<<dim3(NP / 192, BS / 128), 512, 0, stream>>>(
        Apk[cur], Bpk, C0, token, wtok, b_hh, h[cur], h[nxt], Apk[nxt]);
    k_out<<<dim3(BS / 4), 256, 0, stream>>>(h[nxt], W_out, b_out, out, token, t);
  }
  (void)in_sizes; (void)n_in; (void)out_size; (void)ws_size;
}